// Round 1
// baseline (127.320 us; speedup 1.0000x reference)
//
#include <hip/hip_runtime.h>
#include <hip/hip_bf16.h>

typedef __hip_bfloat16 bf16_t;
typedef __attribute__((ext_vector_type(4))) float f32x4;
typedef __attribute__((ext_vector_type(8))) __bf16 bf16x8;
typedef __attribute__((ext_vector_type(8))) short s16x8;
typedef __attribute__((ext_vector_type(4))) unsigned short u16x4;

#define BATCH 16384
#define NDIM  1024
#define HID   512
#define LAT   50

__device__ inline unsigned short f2b_u(float f) {
  union { bf16_t b; unsigned short u; } cv; cv.b = __float2bfloat16(f); return cv.u;
}

// ---------------------------------------------------------------------------
// prep: convert x and all weights to bf16 in ws; pad Wab to [128][512],
// W2 to [512][64] (K padded with zeros), bias_ab to [128] f32.
// ---------------------------------------------------------------------------
__global__ void prep_kernel(const float* __restrict__ x,  const float* __restrict__ W1,
                            const float* __restrict__ W3, const float* __restrict__ Wa,
                            const float* __restrict__ Wb, const float* __restrict__ W2,
                            const float* __restrict__ ba, const float* __restrict__ bb,
                            bf16_t* __restrict__ xb,  bf16_t* __restrict__ w1,
                            bf16_t* __restrict__ w3,  bf16_t* __restrict__ wab,
                            bf16_t* __restrict__ w2p, float* __restrict__ bab)
{
  const int XU   = (BATCH * NDIM) / 4;  // float4 units of x
  const int W1N  = HID * NDIM;
  const int W3N  = NDIM * HID;
  const int WABN = 128 * HID;
  const int W2PN = HID * 64;
  const int TOT  = XU + W1N + W3N + WABN + W2PN + 128;
  for (int i = blockIdx.x * blockDim.x + threadIdx.x; i < TOT;
       i += gridDim.x * blockDim.x) {
    int j = i;
    if (j < XU) {
      const f32x4 v = ((const f32x4*)x)[j];
      u16x4 o;
      o[0] = f2b_u(v[0]); o[1] = f2b_u(v[1]); o[2] = f2b_u(v[2]); o[3] = f2b_u(v[3]);
      ((u16x4*)xb)[j] = o;
      continue;
    }
    j -= XU;
    if (j < W1N) { w1[j] = __float2bfloat16(W1[j]); continue; }
    j -= W1N;
    if (j < W3N) { w3[j] = __float2bfloat16(W3[j]); continue; }
    j -= W3N;
    if (j < WABN) {
      const int n = j >> 9, k = j & 511;
      float v = (n < 50) ? Wa[n * 512 + k] : ((n < 100) ? Wb[(n - 50) * 512 + k] : 0.f);
      wab[j] = __float2bfloat16(v);
      continue;
    }
    j -= WABN;
    if (j < W2PN) {
      const int n = j >> 6, k = j & 63;
      float v = (k < 50) ? W2[n * 50 + k] : 0.f;
      w2p[j] = __float2bfloat16(v);
      continue;
    }
    j -= W2PN;  // bias_ab, 128 entries
    bab[j] = (j < 50) ? ba[j] : ((j < 100) ? bb[j - 50] : 0.f);
  }
}

// ---------------------------------------------------------------------------
// bf16 MFMA GEMM, C[M,N] = act(A[M,K] @ B[N,K]^T + bias[N])
// 128x128 tile, BK=64, 4 waves (2x2 of 64x64), 16x16x32 MFMA.
// LDS [128 rows][8 slots of 16B], slot XOR-swizzled by (row&7) -> conflict-free
// ds_write_b128 staging and ds_read_b128 fragment reads (guide G4/T2).
// ACT: 0=relu, 1=sigmoid, 2=softplus(+1e-4) with alpha/beta split write.
// ---------------------------------------------------------------------------
template<int ACT, int OUT_BF16, int AB_SPLIT>
__global__ __launch_bounds__(256, 2)
void gemm_bt_kernel(const bf16_t* __restrict__ A, const bf16_t* __restrict__ B,
                    const float* __restrict__ bias,
                    void* __restrict__ outv,
                    float* __restrict__ out_a, float* __restrict__ out_b,
                    int M, int N, int K)
{
  __shared__ char lds[(128 + 128) * 64 * 2];
  char* lA = lds;
  char* lB = lds + 128 * 64 * 2;

  const int tid     = threadIdx.x;
  const int mblocks = M >> 7;
  const int bm   = blockIdx.x % mblocks;
  const int bn   = blockIdx.x / mblocks;
  const int wid  = tid >> 6;
  const int lane = tid & 63;
  const int l15  = lane & 15;
  const int l4   = lane >> 4;
  const int wm   = (wid >> 1) << 6;
  const int wn   = (wid & 1) << 6;

  f32x4 acc[4][4] = {};

  for (int k0 = 0; k0 < K; k0 += 64) {
    // stage A,B tiles: 1024 16B cells each, 4 per thread, write-side swizzle
    #pragma unroll
    for (int i = 0; i < 4; ++i) {
      const int c     = i * 256 + tid;
      const int r     = c >> 3;
      const int slog  = c & 7;
      const int sphys = slog ^ (r & 7);
      *(s16x8*)(lA + r * 128 + sphys * 16) =
          *(const s16x8*)(A + (size_t)(bm * 128 + r) * K + k0 + slog * 8);
      *(s16x8*)(lB + r * 128 + sphys * 16) =
          *(const s16x8*)(B + (size_t)(bn * 128 + r) * K + k0 + slog * 8);
    }
    __syncthreads();

    #pragma unroll
    for (int h = 0; h < 2; ++h) {
      bf16x8 af[4], bfr[4];
      #pragma unroll
      for (int mi = 0; mi < 4; ++mi) {
        const int row = wm + mi * 16 + l15;
        const int sp  = (h * 4 + l4) ^ (row & 7);
        af[mi] = *(const bf16x8*)(lA + row * 128 + sp * 16);
      }
      #pragma unroll
      for (int ni = 0; ni < 4; ++ni) {
        const int row = wn + ni * 16 + l15;
        const int sp  = (h * 4 + l4) ^ (row & 7);
        bfr[ni] = *(const bf16x8*)(lB + row * 128 + sp * 16);
      }
      #pragma unroll
      for (int mi = 0; mi < 4; ++mi)
        #pragma unroll
        for (int ni = 0; ni < 4; ++ni)
          acc[mi][ni] = __builtin_amdgcn_mfma_f32_16x16x32_bf16(
              af[mi], bfr[ni], acc[mi][ni], 0, 0, 0);
    }
    __syncthreads();
  }

  // epilogue: C/D layout col=lane&15, row=(lane>>4)*4+reg  (m89-verified)
  #pragma unroll
  for (int ni = 0; ni < 4; ++ni) {
    const int n  = bn * 128 + wn + ni * 16 + l15;
    const float bv = bias[n];
    #pragma unroll
    for (int mi = 0; mi < 4; ++mi) {
      #pragma unroll
      for (int r = 0; r < 4; ++r) {
        const int m   = bm * 128 + wm + mi * 16 + l4 * 4 + r;
        const float t = acc[mi][ni][r] + bv;
        if (AB_SPLIT) {
          const float y = (t > 20.f ? t : log1pf(expf(t))) + 1e-4f;
          if (n < 50)       out_a[(size_t)m * 50 + n] = y;
          else if (n < 100) out_b[(size_t)m * 50 + (n - 50)] = y;
        } else {
          const float y = (ACT == 0) ? fmaxf(t, 0.f) : (1.f / (1.f + expf(-t)));
          if (OUT_BF16) ((bf16_t*)outv)[(size_t)m * N + n] = __float2bfloat16(y);
          else          ((float*)outv)[(size_t)m * N + n] = y;
        }
      }
    }
  }
}

// ---------------------------------------------------------------------------
// stick-breaking: one wave per row. lane k<50 computes v_k, then a 6-step
// shfl_up multiplicative inclusive scan of (1-v) gives the exclusive cumprod.
// Writes pi padded to [B][64] bf16 (cols 50..63 zero).
// ---------------------------------------------------------------------------
__global__ void stick_kernel(const float* __restrict__ u,
                             const float* __restrict__ alpha,
                             const float* __restrict__ beta,
                             bf16_t* __restrict__ pi)
{
  const int gw   = (blockIdx.x * blockDim.x + threadIdx.x) >> 6;
  const int lane = threadIdx.x & 63;
  if (gw >= BATCH) return;
  const size_t row = (size_t)gw;

  float v = 1.f, t = 1.f;
  if (lane < 49) {
    const float a  = alpha[row * 50 + lane];
    const float b  = beta[row * 50 + lane];
    const float uu = u[row * 50 + lane];
    const float tb = powf(uu, 1.f / b);
    v = powf(1.f - tb, 1.f / a);
    t = 1.f - v;
  }
  // lane 49: v forced to 1 (set_v_K_to_one); t=1 keeps scan benign
  float p = t;
  #pragma unroll
  for (int d = 1; d < 64; d <<= 1) {
    const float o = __shfl_up(p, d, 64);
    if (lane >= d) p *= o;
  }
  float e = __shfl_up(p, 1, 64);
  if (lane == 0) e = 1.f;
  const float piv = v * e;
  pi[row * 64 + lane] = __float2bfloat16(lane < 50 ? piv : 0.f);
}

// ---------------------------------------------------------------------------
extern "C" void kernel_launch(void* const* d_in, const int* in_sizes, int n_in,
                              void* d_out, int out_size, void* d_ws, size_t ws_size,
                              hipStream_t stream)
{
  const float* x  = (const float*)d_in[0];
  const float* u  = (const float*)d_in[1];
  const float* W1 = (const float*)d_in[2];
  const float* b1 = (const float*)d_in[3];
  const float* Wa = (const float*)d_in[4];
  const float* ba = (const float*)d_in[5];
  const float* Wb = (const float*)d_in[6];
  const float* bb = (const float*)d_in[7];
  const float* W2 = (const float*)d_in[8];
  const float* b2 = (const float*)d_in[9];
  const float* W3 = (const float*)d_in[10];
  const float* b3 = (const float*)d_in[11];

  float* recon  = (float*)d_out;
  float* oalpha = recon + (size_t)BATCH * NDIM;
  float* obeta  = oalpha + (size_t)BATCH * LAT;

  // ws layout (bytes). xb [0,33.5M) is dead after GEMM1, so h2 (16.7M) and
  // pi (2M @ +16.7M) reuse it. Total footprint: 52,625,920 B.
  char* ws = (char*)d_ws;
  bf16_t* xb  = (bf16_t*)(ws);
  bf16_t* h2  = (bf16_t*)(ws);                 // reuses xb after GEMM1
  bf16_t* pi  = (bf16_t*)(ws + 16777216);      // reuses xb tail
  bf16_t* h   = (bf16_t*)(ws + 33554432);
  bf16_t* w1  = (bf16_t*)(ws + 50331648);
  bf16_t* w3  = (bf16_t*)(ws + 51380224);
  bf16_t* wab = (bf16_t*)(ws + 52428800);
  bf16_t* w2p = (bf16_t*)(ws + 52559872);
  float*  bab = (float*)(ws + 52625408);

  prep_kernel<<<2048, 256, 0, stream>>>(x, W1, W3, Wa, Wb, W2, ba, bb,
                                        xb, w1, w3, wab, w2p, bab);
  // h = relu(x @ W1^T + b1)          [16384,512] bf16
  gemm_bt_kernel<0, 1, 0><<<512, 256, 0, stream>>>(
      xb, w1, b1, (void*)h, nullptr, nullptr, BATCH, HID, NDIM);
  // alpha/beta = softplus(h @ Wab^T + bab) + 1e-4   -> d_out
  gemm_bt_kernel<2, 0, 1><<<128, 256, 0, stream>>>(
      h, wab, bab, nullptr, oalpha, obeta, BATCH, 128, HID);
  // pi (stick-breaking) -> ws, padded [16384,64] bf16
  stick_kernel<<<4096, 256, 0, stream>>>(u, oalpha, obeta, pi);
  // h2 = relu(pi @ W2p^T + b2)       [16384,512] bf16
  gemm_bt_kernel<0, 1, 0><<<512, 256, 0, stream>>>(
      pi, w2p, b2, (void*)h2, nullptr, nullptr, BATCH, HID, 64);
  // recon = sigmoid(h2 @ W3^T + b3)  [16384,1024] f32 -> d_out
  gemm_bt_kernel<1, 0, 0><<<1024, 256, 0, stream>>>(
      h2, w3, b3, (void*)recon, nullptr, nullptr, BATCH, NDIM, HID);
}